// Round 3
// baseline (172.469 us; speedup 1.0000x reference)
//
#include <hip/hip_runtime.h>

// IIR biquad cascade (K=4), B=64, C=2, L=131072 -> 128 independent rows.
// Chunked warm-up parallelization: one lane per S-sample chunk, each lane
// warm-starts W=384 samples early from zero state (truncation ~W^3 r^W with
// r<=0.95 -> absmax ~0.25 vs threshold 2.02; exact at row starts).
// R2: S 128->64 to double wave count (512->1024 blocks, 25%->50% occupancy
// cap) — R1 was latency/occupancy-bound (VALUBusy 41%, HBM 28%, occ 20.8%).
// Redundancy rises 4x->7x but stall exposure halves.
// R2fix: nontemporal store needs a clang ext_vector, not HIP float4.

#define SS   64    // output samples per lane (chunk size)
#define WW   384   // warm-up samples (zero-state spin-up)
#define TT   32    // time-tile staged per LDS round
#define TPB  256   // threads per block (= chunks per block)
#define LSTR 33    // LDS row stride in floats (odd => 2-way = conflict-free)
#define KB   4     // biquads in cascade

typedef float vf4 __attribute__((ext_vector_type(4)));

__global__ __launch_bounds__(TPB) void iir_chunks_kernel(
    const float* __restrict__ x, const float* __restrict__ Bs,
    const float* __restrict__ As, float* __restrict__ out, int L)
{
    __shared__ float lds[TPB * LSTR];
    const int tid = threadIdx.x;
    const int bpr = (L / SS) / TPB;              // blocks per row (8)
    const int row = blockIdx.x / bpr;            // 0..127
    const int chunk0 = (blockIdx.x % bpr) * TPB; // first chunk of this block

    // ---- per-row coefficients (broadcast loads, all lanes same row) ----
    float b0[KB], b1[KB], b2[KB], na1[KB], na2[KB];
    const float* Bp = Bs + (size_t)row * KB * 3;
    const float* Ap = As + (size_t)row * KB * 3;
#pragma unroll
    for (int k = 0; k < KB; ++k) {
        float inv = 1.0f / Ap[3 * k];            // a0 == 1.0 in this problem
        b0[k]  =  Bp[3 * k]     * inv;
        b1[k]  =  Bp[3 * k + 1] * inv;
        b2[k]  =  Bp[3 * k + 2] * inv;
        na1[k] = -Ap[3 * k + 1] * inv;
        na2[k] = -Ap[3 * k + 2] * inv;
    }

    float s1[KB] = {0.f, 0.f, 0.f, 0.f};
    float s2[KB] = {0.f, 0.f, 0.f, 0.f};

    const float* xrow = x   + (size_t)row * L;
    float*       orow = out + (size_t)row * L;
    float*       myrow = lds + tid * LSTR;

    const int NT = (SS + WW) / TT;  // 14 tiles total
    const int WT = WW / TT;         // 12 warm tiles (no output)

#pragma unroll 1
    for (int it = 0; it < NT; ++it) {
        const int i0 = it * TT - WW;  // tile offset relative to chunk start

        // ---- cooperative coalesced load: global -> LDS ----
#pragma unroll
        for (int l = 0; l < (TPB * TT / 4) / TPB; ++l) {   // 8 float4s/thread
            int e  = l * TPB + tid;
            int j  = e >> 3;              // chunk slot 0..255 (TT/4 = 8)
            int p4 = (e & 7) << 2;        // float offset within tile
            int pos = (chunk0 + j) * SS + i0 + p4;  // position within row
            float4 v = make_float4(0.f, 0.f, 0.f, 0.f);
            if (pos >= 0) v = *reinterpret_cast<const float4*>(xrow + pos);
            float* d = lds + j * LSTR + p4;
            d[0] = v.x; d[1] = v.y; d[2] = v.z; d[3] = v.w;
        }
        __syncthreads();

        if (it < WT) {
            // ---- warm-up tile: advance state only ----
#pragma unroll
            for (int p = 0; p < TT; ++p) {
                float u = myrow[p];
#pragma unroll
                for (int k = 0; k < KB; ++k) {
                    float yv = fmaf(b0[k], u, s1[k]);
                    s1[k] = fmaf(na1[k], yv, fmaf(b1[k], u, s2[k]));
                    s2[k] = fmaf(na2[k], yv, b2[k] * u);
                    u = yv;
                }
            }
            __syncthreads();  // protect LDS before next tile's load
        } else {
            // ---- output tile: compute and write y back into LDS ----
#pragma unroll
            for (int p = 0; p < TT; ++p) {
                float u = myrow[p];
#pragma unroll
                for (int k = 0; k < KB; ++k) {
                    float yv = fmaf(b0[k], u, s1[k]);
                    s1[k] = fmaf(na1[k], yv, fmaf(b1[k], u, s2[k]));
                    s2[k] = fmaf(na2[k], yv, b2[k] * u);
                    u = yv;
                }
                myrow[p] = u;
            }
            __syncthreads();

            // ---- cooperative coalesced store: LDS -> global (nontemporal) ----
#pragma unroll
            for (int l = 0; l < 8; ++l) {
                int e  = l * TPB + tid;
                int j  = e >> 3;
                int p4 = (e & 7) << 2;
                int pos = (chunk0 + j) * SS + i0 + p4;  // >= 0 in output tiles
                const float* sp = lds + j * LSTR + p4;
                vf4 v = { sp[0], sp[1], sp[2], sp[3] };
                __builtin_nontemporal_store(v, reinterpret_cast<vf4*>(orow + pos));
            }
            __syncthreads();
        }
    }
}

extern "C" void kernel_launch(void* const* d_in, const int* in_sizes, int n_in,
                              void* d_out, int out_size, void* d_ws, size_t ws_size,
                              hipStream_t stream) {
    const float* x  = (const float*)d_in[0];   // (B, C, L) f32
    const float* Bs = (const float*)d_in[1];   // (B, C, K, 3) f32
    const float* As = (const float*)d_in[2];   // (B, C, K, 3) f32
    float* out = (float*)d_out;                // (B, C, L) f32

    const int rows = in_sizes[1] / (KB * 3);   // B*C = 128
    const int L    = in_sizes[0] / rows;       // 131072
    const int bpr  = (L / SS) / TPB;           // 8 blocks per row
    dim3 grid(rows * bpr), block(TPB);
    hipLaunchKernelGGL(iir_chunks_kernel, grid, block, 0, stream,
                       x, Bs, As, out, L);
}

// Round 4
// 156.846 us; speedup vs baseline: 1.0996x; 1.0996x over previous
//
#include <hip/hip_runtime.h>
#include <math.h>

// IIR biquad cascade (K=4), B=64, C=2, L=131072 -> 128 independent rows.
// Chunked warm-up parallelization: one lane per S=64-sample chunk, warm-started
// from zero state W samples early.
// R4: adaptive per-row W. R3 was memory-delivery-bound (~5.8 TB/s aggregate
// across L2/LLC/HBM; 536 MB demanded). W_row = 25.6/(-ln r_max) nats
// (calibrated: W=384@r=0.95 passed with absmax 0.25 vs thr 2.02, +30% margin),
// clamped [64,384], multiple of TT. Mean W ~150-190 -> read demand ~270 MB.
// Heavy rows dispatched first (LPT) via prep-kernel rank to kill stragglers.

#define SS   64    // output samples per lane (chunk size)
#define WMAX 384   // max warm-up (calibrated at r=0.95)
#define WMIN 64
#define TT   32    // time-tile staged per LDS round
#define TPB  256   // threads per block (= chunks per block)
#define LSTR 33    // LDS row stride in floats (odd => 2-way = conflict-free)
#define KB   4     // biquads in cascade

typedef float vf4 __attribute__((ext_vector_type(4)));

// ---- prep: per-row warm-up length + heavy-first rank (128 rows, 1 block) ----
__global__ void iir_prep_kernel(const float* __restrict__ As, int rows,
                                int* __restrict__ wrow, int* __restrict__ perm)
{
    __shared__ int sw[256];
    const int r = threadIdx.x;
    int W = 0;
    if (r < rows) {
        float r2max = 0.f;
#pragma unroll
        for (int k = 0; k < KB; ++k) {
            float a0 = As[(size_t)r * KB * 3 + 3 * k];
            float a2 = As[(size_t)r * KB * 3 + 3 * k + 2] / a0;   // = r^2
            r2max = fmaxf(r2max, a2);
        }
        float rmax = fminf(fmaxf(sqrtf(fmaxf(r2max, 0.f)), 0.20f), 0.955f);
        float Wf = 25.6f / (-logf(rmax));
        W = ((int)ceilf(Wf) + TT - 1) & ~(TT - 1);
        W = min(max(W, WMIN), WMAX);
        wrow[r] = W;
    }
    sw[r] = W;
    __syncthreads();
    if (r < rows) {
        int rank = 0;
        for (int i = 0; i < rows; ++i)
            rank += (sw[i] > W) || (sw[i] == W && i < r);
        perm[rank] = r;   // perm[slot] = row, heaviest slot first
    }
}

__global__ __launch_bounds__(TPB) void iir_chunks_kernel(
    const float* __restrict__ x, const float* __restrict__ Bs,
    const float* __restrict__ As, float* __restrict__ out, int L,
    const int* __restrict__ wrow, const int* __restrict__ perm)
{
    __shared__ float lds[TPB * LSTR];
    const int tid = threadIdx.x;
    const int bpr = (L / SS) / TPB;                  // blocks per row (8)
    const int row = perm[blockIdx.x / bpr];          // heavy rows first
    const int chunk0 = (blockIdx.x % bpr) * TPB;     // first chunk of block
    const int W = wrow[row];

    // ---- per-row coefficients (broadcast loads, all lanes same row) ----
    float b0[KB], b1[KB], b2[KB], na1[KB], na2[KB];
    const float* Bp = Bs + (size_t)row * KB * 3;
    const float* Ap = As + (size_t)row * KB * 3;
#pragma unroll
    for (int k = 0; k < KB; ++k) {
        float inv = 1.0f / Ap[3 * k];                // a0 == 1.0 here
        b0[k]  =  Bp[3 * k]     * inv;
        b1[k]  =  Bp[3 * k + 1] * inv;
        b2[k]  =  Bp[3 * k + 2] * inv;
        na1[k] = -Ap[3 * k + 1] * inv;
        na2[k] = -Ap[3 * k + 2] * inv;
    }

    float s1[KB] = {0.f, 0.f, 0.f, 0.f};
    float s2[KB] = {0.f, 0.f, 0.f, 0.f};

    const float* xrow = x   + (size_t)row * L;
    float*       orow = out + (size_t)row * L;
    float*       myrow = lds + tid * LSTR;

    const int NT = (SS + W) / TT;   // total tiles (runtime, 4..14)
    const int WT = W / TT;          // warm tiles (no output)

#pragma unroll 1
    for (int it = 0; it < NT; ++it) {
        const int i0 = it * TT - W;  // tile offset relative to chunk start

        // ---- cooperative coalesced load: global -> LDS ----
#pragma unroll
        for (int l = 0; l < (TPB * TT / 4) / TPB; ++l) {   // 8 float4s/thread
            int e  = l * TPB + tid;
            int j  = e >> 3;              // chunk slot 0..255 (TT/4 = 8)
            int p4 = (e & 7) << 2;        // float offset within tile
            int pos = (chunk0 + j) * SS + i0 + p4;  // position within row
            float4 v = make_float4(0.f, 0.f, 0.f, 0.f);
            if (pos >= 0) v = *reinterpret_cast<const float4*>(xrow + pos);
            float* d = lds + j * LSTR + p4;
            d[0] = v.x; d[1] = v.y; d[2] = v.z; d[3] = v.w;
        }
        __syncthreads();

        if (it < WT) {
            // ---- warm-up tile: advance state only ----
#pragma unroll
            for (int p = 0; p < TT; ++p) {
                float u = myrow[p];
#pragma unroll
                for (int k = 0; k < KB; ++k) {
                    float yv = fmaf(b0[k], u, s1[k]);
                    s1[k] = fmaf(na1[k], yv, fmaf(b1[k], u, s2[k]));
                    s2[k] = fmaf(na2[k], yv, b2[k] * u);
                    u = yv;
                }
            }
            __syncthreads();  // protect LDS before next tile's load
        } else {
            // ---- output tile: compute and write y back into LDS ----
#pragma unroll
            for (int p = 0; p < TT; ++p) {
                float u = myrow[p];
#pragma unroll
                for (int k = 0; k < KB; ++k) {
                    float yv = fmaf(b0[k], u, s1[k]);
                    s1[k] = fmaf(na1[k], yv, fmaf(b1[k], u, s2[k]));
                    s2[k] = fmaf(na2[k], yv, b2[k] * u);
                    u = yv;
                }
                myrow[p] = u;
            }
            __syncthreads();

            // ---- cooperative coalesced store: LDS -> global (nontemporal) ----
#pragma unroll
            for (int l = 0; l < 8; ++l) {
                int e  = l * TPB + tid;
                int j  = e >> 3;
                int p4 = (e & 7) << 2;
                int pos = (chunk0 + j) * SS + i0 + p4;  // >= 0 in output tiles
                const float* sp = lds + j * LSTR + p4;
                vf4 v = { sp[0], sp[1], sp[2], sp[3] };
                __builtin_nontemporal_store(v, reinterpret_cast<vf4*>(orow + pos));
            }
            __syncthreads();
        }
    }
}

extern "C" void kernel_launch(void* const* d_in, const int* in_sizes, int n_in,
                              void* d_out, int out_size, void* d_ws, size_t ws_size,
                              hipStream_t stream) {
    const float* x  = (const float*)d_in[0];   // (B, C, L) f32
    const float* Bs = (const float*)d_in[1];   // (B, C, K, 3) f32
    const float* As = (const float*)d_in[2];   // (B, C, K, 3) f32
    float* out = (float*)d_out;                // (B, C, L) f32

    const int rows = in_sizes[1] / (KB * 3);   // B*C = 128
    const int L    = in_sizes[0] / rows;       // 131072
    const int bpr  = (L / SS) / TPB;           // 8 blocks per row

    int* wrow = (int*)d_ws;                    // rows ints
    int* perm = wrow + rows;                   // rows ints

    hipLaunchKernelGGL(iir_prep_kernel, dim3(1), dim3(256), 0, stream,
                       As, rows, wrow, perm);
    hipLaunchKernelGGL(iir_chunks_kernel, dim3(rows * bpr), dim3(TPB), 0, stream,
                       x, Bs, As, out, L, wrow, perm);
}

// Round 5
// 141.318 us; speedup vs baseline: 1.2204x; 1.1099x over previous
//
#include <hip/hip_runtime.h>
#include <math.h>

// IIR biquad cascade (K=4), B=64, C=2, L=131072 -> 128 independent rows.
// Chunked warm-up parallelization: one lane per S=64-sample chunk, warm-started
// from zero state W samples early. Adaptive per-row W (R4): W = 25.6 nats /
// (-ln rmax), clamped [64,384]; heavy rows dispatched first (LPT).
// R5: register prefetch across the barrier. R4 was latency-bound (VALUBusy 44%,
// HBM 29%, occ 30%): each tile did load->syncthreads->compute with zero
// prefetch distance, eating full L2/HBM latency at every barrier. Now tile
// it+1's global loads issue right after tile it's LDS store and stay in
// flight (VGPR dest => no vmcnt drain at s_barrier) behind the 1280-cycle
// compute phase.

#define SS   64    // output samples per lane (chunk size)
#define WMAX 384   // max warm-up (calibrated at r=0.95)
#define WMIN 64
#define TT   32    // time-tile staged per LDS round
#define TPB  256   // threads per block (= chunks per block)
#define LSTR 33    // LDS row stride in floats (odd => 2-way = conflict-free)
#define KB   4     // biquads in cascade
#define NL   8     // float4 loads per thread per tile (TPB*TT/4/TPB)

typedef float vf4 __attribute__((ext_vector_type(4)));

// ---- prep: per-row warm-up length + heavy-first rank (128 rows, 1 block) ----
__global__ void iir_prep_kernel(const float* __restrict__ As, int rows,
                                int* __restrict__ wrow, int* __restrict__ perm)
{
    __shared__ int sw[256];
    const int r = threadIdx.x;
    int W = 0;
    if (r < rows) {
        float r2max = 0.f;
#pragma unroll
        for (int k = 0; k < KB; ++k) {
            float a0 = As[(size_t)r * KB * 3 + 3 * k];
            float a2 = As[(size_t)r * KB * 3 + 3 * k + 2] / a0;   // = r^2
            r2max = fmaxf(r2max, a2);
        }
        float rmax = fminf(fmaxf(sqrtf(fmaxf(r2max, 0.f)), 0.20f), 0.955f);
        float Wf = 25.6f / (-logf(rmax));
        W = ((int)ceilf(Wf) + TT - 1) & ~(TT - 1);
        W = min(max(W, WMIN), WMAX);
        wrow[r] = W;
    }
    sw[r] = W;
    __syncthreads();
    if (r < rows) {
        int rank = 0;
        for (int i = 0; i < rows; ++i)
            rank += (sw[i] > W) || (sw[i] == W && i < r);
        perm[rank] = r;   // perm[slot] = row, heaviest slot first
    }
}

__global__ __launch_bounds__(TPB, 4) void iir_chunks_kernel(
    const float* __restrict__ x, const float* __restrict__ Bs,
    const float* __restrict__ As, float* __restrict__ out, int L,
    const int* __restrict__ wrow, const int* __restrict__ perm)
{
    __shared__ float lds[TPB * LSTR];
    const int tid = threadIdx.x;
    const int bpr = (L / SS) / TPB;                  // blocks per row (8)
    const int row = perm[blockIdx.x / bpr];          // heavy rows first
    const int chunk0 = (blockIdx.x % bpr) * TPB;     // first chunk of block
    const int W = wrow[row];

    // ---- per-row coefficients (broadcast loads, all lanes same row) ----
    float b0[KB], b1[KB], b2[KB], na1[KB], na2[KB];
    const float* Bp = Bs + (size_t)row * KB * 3;
    const float* Ap = As + (size_t)row * KB * 3;
#pragma unroll
    for (int k = 0; k < KB; ++k) {
        float inv = 1.0f / Ap[3 * k];                // a0 == 1.0 here
        b0[k]  =  Bp[3 * k]     * inv;
        b1[k]  =  Bp[3 * k + 1] * inv;
        b2[k]  =  Bp[3 * k + 2] * inv;
        na1[k] = -Ap[3 * k + 1] * inv;
        na2[k] = -Ap[3 * k + 2] * inv;
    }

    float s1[KB] = {0.f, 0.f, 0.f, 0.f};
    float s2[KB] = {0.f, 0.f, 0.f, 0.f};

    const float* xrow = x   + (size_t)row * L;
    float*       orow = out + (size_t)row * L;
    float*       myrow = lds + tid * LSTR;

    // Loader mapping (constant per thread): e = l*TPB+tid ->
    //   chunk slot j = l*32 + (tid>>3), float offset p4 = (tid&7)*4.
    const int tq = tid >> 3;
    const int p4 = (tid & 7) << 2;
    int off[NL];        // global float offset of this thread's l-th load at it=0
    int ldsoff[NL];     // LDS float offset of the same
#pragma unroll
    for (int l = 0; l < NL; ++l) {
        int j = l * 32 + tq;
        off[l]    = (chunk0 + j) * SS + p4 - W;
        ldsoff[l] = j * LSTR + p4;
    }

    const int NT = (SS + W) / TT;   // total tiles (runtime, 4..14)
    const int WT = W / TT;          // warm tiles (no output)

    // ---- prologue: prefetch tile 0 into registers ----
    float4 rn[NL];
#pragma unroll
    for (int l = 0; l < NL; ++l) {
        int pos = off[l];
        rn[l] = make_float4(0.f, 0.f, 0.f, 0.f);
        if (pos >= 0) rn[l] = *reinterpret_cast<const float4*>(xrow + pos);
    }

#pragma unroll 1
    for (int it = 0; it < NT; ++it) {
        __syncthreads();   // previous tile's LDS consumers are done

        // ---- registers -> LDS (this tile's data) ----
#pragma unroll
        for (int l = 0; l < NL; ++l) {
            float* d = lds + ldsoff[l];
            d[0] = rn[l].x; d[1] = rn[l].y; d[2] = rn[l].z; d[3] = rn[l].w;
        }

        // ---- prefetch next tile into registers (stays in flight) ----
        if (it + 1 < NT) {
            const int base = (it + 1) * TT;
#pragma unroll
            for (int l = 0; l < NL; ++l) {
                int pos = off[l] + base;
                rn[l] = make_float4(0.f, 0.f, 0.f, 0.f);
                if (pos >= 0) rn[l] = *reinterpret_cast<const float4*>(xrow + pos);
            }
        }

        __syncthreads();   // this tile's LDS data visible

        if (it < WT) {
            // ---- warm-up tile: advance state only ----
#pragma unroll
            for (int p = 0; p < TT; ++p) {
                float u = myrow[p];
#pragma unroll
                for (int k = 0; k < KB; ++k) {
                    float yv = fmaf(b0[k], u, s1[k]);
                    s1[k] = fmaf(na1[k], yv, fmaf(b1[k], u, s2[k]));
                    s2[k] = fmaf(na2[k], yv, b2[k] * u);
                    u = yv;
                }
            }
        } else {
            // ---- output tile: compute, y back into LDS, coalesced store ----
#pragma unroll
            for (int p = 0; p < TT; ++p) {
                float u = myrow[p];
#pragma unroll
                for (int k = 0; k < KB; ++k) {
                    float yv = fmaf(b0[k], u, s1[k]);
                    s1[k] = fmaf(na1[k], yv, fmaf(b1[k], u, s2[k]));
                    s2[k] = fmaf(na2[k], yv, b2[k] * u);
                    u = yv;
                }
                myrow[p] = u;
            }
            __syncthreads();

            const int base = it * TT - W;  // >= 0 here
#pragma unroll
            for (int l = 0; l < NL; ++l) {
                const float* sp = lds + ldsoff[l];
                vf4 v = { sp[0], sp[1], sp[2], sp[3] };
                __builtin_nontemporal_store(
                    v, reinterpret_cast<vf4*>(orow + off[l] + W + base));
            }
        }
    }
}

extern "C" void kernel_launch(void* const* d_in, const int* in_sizes, int n_in,
                              void* d_out, int out_size, void* d_ws, size_t ws_size,
                              hipStream_t stream) {
    const float* x  = (const float*)d_in[0];   // (B, C, L) f32
    const float* Bs = (const float*)d_in[1];   // (B, C, K, 3) f32
    const float* As = (const float*)d_in[2];   // (B, C, K, 3) f32
    float* out = (float*)d_out;                // (B, C, L) f32

    const int rows = in_sizes[1] / (KB * 3);   // B*C = 128
    const int L    = in_sizes[0] / rows;       // 131072
    const int bpr  = (L / SS) / TPB;           // 8 blocks per row

    int* wrow = (int*)d_ws;                    // rows ints
    int* perm = wrow + rows;                   // rows ints

    hipLaunchKernelGGL(iir_prep_kernel, dim3(1), dim3(256), 0, stream,
                       As, rows, wrow, perm);
    hipLaunchKernelGGL(iir_chunks_kernel, dim3(rows * bpr), dim3(TPB), 0, stream,
                       x, Bs, As, out, L, wrow, perm);
}